// Round 16
// baseline (561.564 us; speedup 1.0000x reference)
//
#include <hip/hip_runtime.h>
#include <cstddef>
#include <cstdint>

// Problem constants
#define BB 64
#define SS 1024
#define DDIM 128
#define NH 4
#define HDIM 32
#define HIDD 512
#define EPSF 1e-5f
#define SCALEF 0.17677669529663687f   // 1/sqrt(32)
#define LOG2E 1.4426950408889634f

typedef __attribute__((ext_vector_type(8))) short short8;
typedef __attribute__((ext_vector_type(4))) short short4_t;
typedef __attribute__((ext_vector_type(4))) float f32x4;
typedef unsigned short ushort_t;

__device__ __forceinline__ unsigned short f2bf(float f) {
  unsigned u = __builtin_bit_cast(unsigned, f);
  unsigned r = (u + 0x7FFFu + ((u >> 16) & 1u)) >> 16;
  return (unsigned short)r;
}
__device__ __forceinline__ float bf2f(ushort_t h) {
  unsigned u = ((unsigned)h) << 16;
  return __builtin_bit_cast(float, u);
}

// ---------------- K0: weight transpose+convert via LDS tiles ----------------
__global__ __launch_bounds__(256) void k_cvtw(
    const float* __restrict__ Wq, const float* __restrict__ Wk,
    const float* __restrict__ Wv, const float* __restrict__ W1,
    const float* __restrict__ W2,
    ushort_t* __restrict__ WqT, ushort_t* __restrict__ WkT,
    ushort_t* __restrict__ WvT, ushort_t* __restrict__ W1T,
    ushort_t* __restrict__ W2T) {
  __shared__ float tile[32][33];
  const int bid = blockIdx.x;
  const float* src; ushort_t* dst; int K, N, t0;
  if (bid < 16)       { src = Wq; dst = WqT; K = 128; N = 128; t0 = bid; }
  else if (bid < 32)  { src = Wk; dst = WkT; K = 128; N = 128; t0 = bid - 16; }
  else if (bid < 48)  { src = Wv; dst = WvT; K = 128; N = 128; t0 = bid - 32; }
  else if (bid < 112) { src = W1; dst = W1T; K = 128; N = 512; t0 = bid - 48; }
  else                { src = W2; dst = W2T; K = 512; N = 128; t0 = bid - 112; }
  const int ntile = N >> 5;
  const int k0 = (t0 / ntile) * 32, n0 = (t0 % ntile) * 32;
  const int t = threadIdx.x;
  const int r = t >> 3, c = (t & 7) * 4;
  float4 v = *(const float4*)(src + (size_t)(k0 + r) * N + n0 + c);
  tile[r][c] = v.x; tile[r][c + 1] = v.y; tile[r][c + 2] = v.z; tile[r][c + 3] = v.w;
  __syncthreads();
  ushort4 o;
  o.x = f2bf(tile[c + 0][r]); o.y = f2bf(tile[c + 1][r]);
  o.z = f2bf(tile[c + 2][r]); o.w = f2bf(tile[c + 3][r]);
  *(ushort4*)(dst + (size_t)(n0 + r) * K + k0 + c) = o;
}

// ---------------- K1: LN1 + masks, 32 lanes/row, float4 ----------------
__global__ __launch_bounds__(256) void k_ln1(const float* __restrict__ seq,
    const float* __restrict__ g1, const float* __restrict__ be1,
    ushort_t* __restrict__ q_in16, ushort_t* __restrict__ seq16,
    float* __restrict__ qmask, float* __restrict__ kmask) {
  const int t = threadIdx.x;
  const int r = t >> 5, cl = (t & 31) * 4;
  const int row = blockIdx.x * 8 + r;
  const size_t base = (size_t)row * DDIM + cl;
  const f32x4 v4 = *(const f32x4*)(seq + base);
  float sum = v4[0] + v4[1] + v4[2] + v4[3];
  float asum = fabsf(v4[0]) + fabsf(v4[1]) + fabsf(v4[2]) + fabsf(v4[3]);
  #pragma unroll
  for (int o = 1; o < 32; o <<= 1) { sum += __shfl_xor(sum, o); asum += __shfl_xor(asum, o); }
  const float mean = sum * (1.f / DDIM);
  f32x4 d;
  #pragma unroll
  for (int j = 0; j < 4; ++j) d[j] = v4[j] - mean;
  float sq = d[0] * d[0] + d[1] * d[1] + d[2] * d[2] + d[3] * d[3];
  #pragma unroll
  for (int o = 1; o < 32; o <<= 1) sq += __shfl_xor(sq, o);
  const float rsq = rsqrtf(sq * (1.f / DDIM) + EPSF);
  const float4 g4 = *(const float4*)(g1 + cl);
  const float4 b4 = *(const float4*)(be1 + cl);
  float qv[4];
  qv[0] = d[0] * rsq * g4.x + b4.x; qv[1] = d[1] * rsq * g4.y + b4.y;
  qv[2] = d[2] * rsq * g4.z + b4.z; qv[3] = d[3] * rsq * g4.w + b4.w;
  short4_t q4, s4;
  #pragma unroll
  for (int j = 0; j < 4; ++j) { q4[j] = (short)f2bf(qv[j]); s4[j] = (short)f2bf(v4[j]); }
  *(short4_t*)(q_in16 + base) = q4;
  *(short4_t*)(seq16 + base) = s4;
  float aq = fabsf(qv[0]) + fabsf(qv[1]) + fabsf(qv[2]) + fabsf(qv[3]);
  #pragma unroll
  for (int o = 1; o < 32; o <<= 1) aq += __shfl_xor(aq, o);
  if ((t & 31) == 0) {
    kmask[row] = asum > 0.f ? 1.f : 0.f;
    qmask[row] = aq > 0.f ? 1.f : 0.f;
  }
}

// ---------------- K2: QKV projections via MFMA (Q | K+V merged) ----------------
__global__ __launch_bounds__(256) void k_qkv_mfma(
    const ushort_t* __restrict__ q_in16, const ushort_t* __restrict__ seq16,
    const ushort_t* __restrict__ WqT, const ushort_t* __restrict__ WkT,
    const ushort_t* __restrict__ WvT,
    const float* __restrict__ bq, const float* __restrict__ bk,
    const float* __restrict__ bv,
    ushort_t* __restrict__ Qo, ushort_t* __restrict__ Ko,
    ushort_t* __restrict__ Vo) {
  const int m = blockIdx.y;
  const int t = threadIdx.x, w = t >> 6, lane = t & 63;
  const int lr = lane & 15, lg = lane >> 4;
  const int row = blockIdx.x * 64 + w * 16;

  if (m == 0) {
    const float sc = SCALEF * LOG2E;
    short8 a[4];
    #pragma unroll
    for (int s = 0; s < 4; ++s)
      a[s] = *(const short8*)(q_in16 + (size_t)(row + lr) * DDIM + s * 32 + lg * 8);
    #pragma unroll
    for (int nt = 0; nt < 8; ++nt) {
      f32x4 acc = {0.f, 0.f, 0.f, 0.f};
      #pragma unroll
      for (int s = 0; s < 4; ++s) {
        short8 b = *(const short8*)(WqT + (size_t)(nt * 16 + lr) * DDIM + s * 32 + lg * 8);
        acc = __builtin_amdgcn_mfma_f32_16x16x32_bf16(b, a[s], acc, 0, 0, 0);
      }
      const int n0 = nt * 16 + lg * 4;
      const float4 bb4 = *(const float4*)(bq + n0);
      short4_t o4;
      o4[0] = (short)f2bf((acc[0] + bb4.x) * sc);
      o4[1] = (short)f2bf((acc[1] + bb4.y) * sc);
      o4[2] = (short)f2bf((acc[2] + bb4.z) * sc);
      o4[3] = (short)f2bf((acc[3] + bb4.w) * sc);
      *(short4_t*)(Qo + (size_t)(row + lr) * DDIM + n0) = o4;
    }
  } else {
    short8 a[4];
    #pragma unroll
    for (int s = 0; s < 4; ++s)
      a[s] = *(const short8*)(seq16 + (size_t)(row + lr) * DDIM + s * 32 + lg * 8);
    #pragma unroll
    for (int nt = 0; nt < 8; ++nt) {
      f32x4 accK = {0.f, 0.f, 0.f, 0.f}, accV = {0.f, 0.f, 0.f, 0.f};
      #pragma unroll
      for (int s = 0; s < 4; ++s) {
        short8 bk8 = *(const short8*)(WkT + (size_t)(nt * 16 + lr) * DDIM + s * 32 + lg * 8);
        short8 bv8 = *(const short8*)(WvT + (size_t)(nt * 16 + lr) * DDIM + s * 32 + lg * 8);
        accK = __builtin_amdgcn_mfma_f32_16x16x32_bf16(bk8, a[s], accK, 0, 0, 0);
        accV = __builtin_amdgcn_mfma_f32_16x16x32_bf16(bv8, a[s], accV, 0, 0, 0);
      }
      const int n0 = nt * 16 + lg * 4;
      const float4 bk4 = *(const float4*)(bk + n0);
      const float4 bv4 = *(const float4*)(bv + n0);
      short4_t k4, v4;
      k4[0] = (short)f2bf(accK[0] + bk4.x); v4[0] = (short)f2bf(accV[0] + bv4.x);
      k4[1] = (short)f2bf(accK[1] + bk4.y); v4[1] = (short)f2bf(accV[1] + bv4.y);
      k4[2] = (short)f2bf(accK[2] + bk4.z); v4[2] = (short)f2bf(accV[2] + bv4.z);
      k4[3] = (short)f2bf(accK[3] + bk4.w); v4[3] = (short)f2bf(accV[3] + bv4.w);
      *(short4_t*)(Ko + (size_t)(row + lr) * DDIM + n0) = k4;
      *(short4_t*)(Vo + (size_t)(row + lr) * DDIM + n0) = v4;
    }
  }
}

// ---------------- K3: attention (R14) + barrier-free pass 1 (K direct from L2) --
// 1D grid 4096, XCD-aware swizzle: all 16 q-blocks of a (b,h) group on one XCD.
__global__ __launch_bounds__(256) void k_attn_mfma(
    const ushort_t* __restrict__ Q, const ushort_t* __restrict__ K,
    const ushort_t* __restrict__ V,
    const float* __restrict__ qmask, const float* __restrict__ kmask,
    float* __restrict__ attn, float* __restrict__ xo) {
  __shared__ __align__(16) ushort_t Ks[2][64 * 40];   // K chunk [k][d] (pass 2)
  __shared__ __align__(16) ushort_t Vts[2][32 * 72];  // V^T chunk [d][k] (pass 2)
  __shared__ __align__(16) ushort_t Wb[4][16 * 88];

  const int t = threadIdx.x;
  const int w = t >> 6, lane = t & 63, lr = lane & 15, lg = lane >> 4;
  // decode swizzled block id
  const int p = blockIdx.x;
  const int xcd = p & 7, kk_ = p >> 3;
  const int m = kk_ & 15, ghi = kk_ >> 4;
  const int g = xcd + 8 * ghi;          // g = h + 4*b
  const int h = g & 3, b = g >> 2;
  const int qi = 15 - m;                // heavy blocks dispatch first
  const int q0 = qi << 6;
  const int kend = q0 + 64;
  const int nch = kend >> 6;

  const size_t bS = (size_t)b * SS;
  const ushort_t* Qh = Q + bS * DDIM + h * HDIM;
  const ushort_t* Kh = K + bS * DDIM + h * HDIM;
  const ushort_t* Vh = V + bS * DDIM + h * HDIM;
  float* attn_bh = attn + (size_t)(b * NH + h) * ((size_t)SS * SS);

  // zero-fill attn[q0:q0+64, kend:SS) with nontemporal stores
  {
    const int cnt4 = (SS - kend) >> 2;
    const f32x4 z = {0.f, 0.f, 0.f, 0.f};
    for (int r = w; r < 64; r += 4) {
      float* rowp = attn_bh + (size_t)(q0 + r) * SS + kend;
      for (int c = lane; c < cnt4; c += 64)
        __builtin_nontemporal_store(z, (f32x4*)(rowp + (size_t)c * 4));
    }
  }

  const int qrow = q0 + w * 16 + lr;       // this lane's q-row
  const short8 qf = *(const short8*)(Qh + (size_t)qrow * DDIM + lg * 8);

  // cooperative staging indices for pass 2: K row (t>>2), 16B slice (t&3)
  const int skr = t >> 2, skc = (t & 3) * 8;

  // ---- pass 1: barrier-free; K fragments direct from global (L2-resident) ----
  float lsum = 0.f;
  for (int c = 0; c < nch; ++c) {
    const int kc = c << 6;
    short8 kf[4];
    #pragma unroll
    for (int T = 0; T < 4; ++T)
      kf[T] = *(const short8*)(Kh + (size_t)(kc + T * 16 + lr) * DDIM + lg * 8);
    f32x4 acc[4];
    #pragma unroll
    for (int T = 0; T < 4; ++T)
      acc[T] = __builtin_amdgcn_mfma_f32_16x16x32_bf16(kf[T], qf,
                                                       (f32x4){0.f, 0.f, 0.f, 0.f}, 0, 0, 0);
    #pragma unroll
    for (int T = 0; T < 4; ++T) {
      const int k0 = kc + T * 16 + lg * 4;
      const float4 km4 = *(const float4*)(kmask + bS + k0);
      #pragma unroll
      for (int r = 0; r < 4; ++r) {
        const float kmv = r == 0 ? km4.x : (r == 1 ? km4.y : (r == 2 ? km4.z : km4.w));
        const bool dead = (kmv == 0.f) || (k0 + r > qrow);
        lsum += dead ? 0.f : exp2f(acc[T][r]);
      }
    }
  }
  float ssum = lsum;
  ssum += __shfl_xor(ssum, 16);
  ssum += __shfl_xor(ssum, 32);
  const float qm = qmask[bS + qrow];
  const float inv = (ssum > 0.f) ? qm / ssum : 0.f;

  // ---- pass 2: staged (R14), recompute scores, nt stores, PV via MFMA (O^T) ----
  ushort_t* myW = &Wb[w][0];
  f32x4 o0 = {0.f, 0.f, 0.f, 0.f}, o1 = {0.f, 0.f, 0.f, 0.f};

  {
    short8 kreg = *(const short8*)(Kh + (size_t)skr * DDIM + skc);
    short8 vreg = *(const short8*)(Vh + (size_t)lane * DDIM + w * 8);
    *(short8*)(Ks[0] + skr * 40 + skc) = kreg;
    #pragma unroll
    for (int j = 0; j < 8; ++j) Vts[0][(w * 8 + j) * 72 + lane] = (ushort_t)vreg[j];
    __syncthreads();
    for (int c = 0; c < nch; ++c) {
      const int kc = c << 6;
      const int cur = c & 1;
      if (c + 1 < nch) {
        kreg = *(const short8*)(Kh + (size_t)(kc + 64 + skr) * DDIM + skc);
        vreg = *(const short8*)(Vh + (size_t)(kc + 64 + lane) * DDIM + w * 8);
      }
      short8 kf[4];
      #pragma unroll
      for (int T = 0; T < 4; ++T)
        kf[T] = *(const short8*)(Ks[cur] + (T * 16 + lr) * 40 + lg * 8);
      f32x4 acc[4];
      #pragma unroll
      for (int T = 0; T < 4; ++T)
        acc[T] = __builtin_amdgcn_mfma_f32_16x16x32_bf16(kf[T], qf,
                                                         (f32x4){0.f, 0.f, 0.f, 0.f}, 0, 0, 0);
      #pragma unroll
      for (int T = 0; T < 4; ++T) {
        const int k0 = kc + T * 16 + lg * 4;
        const float4 km4 = *(const float4*)(kmask + bS + k0);
        f32x4 wv4;
        #pragma unroll
        for (int r = 0; r < 4; ++r) {
          const float kmv = r == 0 ? km4.x : (r == 1 ? km4.y : (r == 2 ? km4.z : km4.w));
          const bool dead = (kmv == 0.f) || (k0 + r > qrow);
          wv4[r] = dead ? 0.f : exp2f(acc[T][r]) * inv;
        }
        __builtin_nontemporal_store(wv4, (f32x4*)(attn_bh + (size_t)qrow * SS + k0));
        short4_t p4;
        p4[0] = (short)f2bf(wv4[0]); p4[1] = (short)f2bf(wv4[1]);
        p4[2] = (short)f2bf(wv4[2]); p4[3] = (short)f2bf(wv4[3]);
        *(short4_t*)(myW + lr * 88 + T * 16 + lg * 4) = p4;
      }
      // PV: O^T = mfma(V^T rows, w rows) -> C[d][q]
      const short8 af0 = *(const short8*)(myW + lr * 88 + lg * 8);
      const short8 af1 = *(const short8*)(myW + lr * 88 + 32 + lg * 8);
      const short8 vb00 = *(const short8*)(Vts[cur] + (size_t)(lr) * 72 + lg * 8);
      const short8 vb10 = *(const short8*)(Vts[cur] + (size_t)(lr) * 72 + 32 + lg * 8);
      const short8 vb01 = *(const short8*)(Vts[cur] + (size_t)(16 + lr) * 72 + lg * 8);
      const short8 vb11 = *(const short8*)(Vts[cur] + (size_t)(16 + lr) * 72 + 32 + lg * 8);
      o0 = __builtin_amdgcn_mfma_f32_16x16x32_bf16(vb00, af0, o0, 0, 0, 0);
      o0 = __builtin_amdgcn_mfma_f32_16x16x32_bf16(vb10, af1, o0, 0, 0, 0);
      o1 = __builtin_amdgcn_mfma_f32_16x16x32_bf16(vb01, af0, o1, 0, 0, 0);
      o1 = __builtin_amdgcn_mfma_f32_16x16x32_bf16(vb11, af1, o1, 0, 0, 0);
      if (c + 1 < nch) {
        *(short8*)(Ks[cur ^ 1] + skr * 40 + skc) = kreg;
        #pragma unroll
        for (int j = 0; j < 8; ++j) Vts[cur ^ 1][(w * 8 + j) * 72 + lane] = (ushort_t)vreg[j];
      }
      __syncthreads();
    }
  }

  {
    float* op = xo + (bS + qrow) * DDIM + h * HDIM;
    *(f32x4*)(op + lg * 4) = o0;
    *(f32x4*)(op + 16 + lg * 4) = o1;
  }
}

// ---------------- K4: fused LN2 + MLP + residual + mask ----------------
__global__ __launch_bounds__(256) void k_mlp_fused(
    const float* __restrict__ xo, const ushort_t* __restrict__ q_in16,
    const float* __restrict__ g2, const float* __restrict__ be2,
    const ushort_t* __restrict__ W1T, const float* __restrict__ bm1,
    const ushort_t* __restrict__ W2T, const float* __restrict__ bm2,
    const float* __restrict__ mask, float* __restrict__ y) {
  __shared__ __align__(16) ushort_t xls[64 * 136];   // LN2 output, bf16
  __shared__ __align__(16) ushort_t hs[4][16 * 140];
  const int t = threadIdx.x, w = t >> 6, lane = t & 63;
  const int lr = lane & 15, lg = lane >> 4;
  const int row0 = blockIdx.x * 64;

  {
    const int r = t >> 2, s = t & 3;
    const size_t base = (size_t)(row0 + r) * DDIM + s * 32;
    float v[32];
    float sum = 0.f, sq = 0.f;
    #pragma unroll
    for (int i = 0; i < 4; ++i) {
      const f32x4 x4a = *(const f32x4*)(xo + base + i * 8);
      const f32x4 x4b = *(const f32x4*)(xo + base + i * 8 + 4);
      const short8 q8 = *(const short8*)(q_in16 + base + i * 8);
      #pragma unroll
      for (int j = 0; j < 4; ++j) {
        v[i * 8 + j] = x4a[j] + bf2f((ushort_t)q8[j]);
        v[i * 8 + 4 + j] = x4b[j] + bf2f((ushort_t)q8[4 + j]);
      }
    }
    #pragma unroll
    for (int i = 0; i < 32; ++i) { sum += v[i]; sq += v[i] * v[i]; }
    sum += __shfl_xor(sum, 1); sum += __shfl_xor(sum, 2);
    sq  += __shfl_xor(sq, 1);  sq  += __shfl_xor(sq, 2);
    const float mean = sum * (1.f / DDIM);
    const float var = sq * (1.f / DDIM) - mean * mean;
    const float rsq = rsqrtf(var + EPSF);
    #pragma unroll
    for (int i = 0; i < 8; ++i) {
      const f32x4 g4 = *(const f32x4*)(g2 + s * 32 + i * 4);
      const f32x4 b4 = *(const f32x4*)(be2 + s * 32 + i * 4);
      short4_t o4;
      #pragma unroll
      for (int j = 0; j < 4; ++j)
        o4[j] = (short)f2bf((v[i * 4 + j] - mean) * rsq * g4[j] + b4[j]);
      *(short4_t*)(xls + r * 136 + s * 32 + i * 4) = o4;
    }
  }
  __syncthreads();

  ushort_t* myh = &hs[w][0];
  short8 xa[4];
  #pragma unroll
  for (int s = 0; s < 4; ++s)
    xa[s] = *(const short8*)(xls + (w * 16 + lr) * 136 + s * 32 + lg * 8);

  f32x4 yacc[8];
  #pragma unroll
  for (int i = 0; i < 8; ++i) yacc[i] = (f32x4){0.f, 0.f, 0.f, 0.f};

  for (int c = 0; c < 4; ++c) {
    #pragma unroll
    for (int nt = 0; nt < 8; ++nt) {
      f32x4 acc = {0.f, 0.f, 0.f, 0.f};
      #pragma unroll
      for (int s = 0; s < 4; ++s) {
        short8 b = *(const short8*)(W1T + (size_t)(c * 128 + nt * 16 + lr) * DDIM + s * 32 + lg * 8);
        acc = __builtin_amdgcn_mfma_f32_16x16x32_bf16(b, xa[s], acc, 0, 0, 0);
      }
      const int n0 = nt * 16 + lg * 4;
      const float4 bb4 = *(const float4*)(bm1 + c * 128 + n0);
      short4_t hp;
      hp[0] = (short)f2bf(fmaxf(acc[0] + bb4.x, 0.f));
      hp[1] = (short)f2bf(fmaxf(acc[1] + bb4.y, 0.f));
      hp[2] = (short)f2bf(fmaxf(acc[2] + bb4.z, 0.f));
      hp[3] = (short)f2bf(fmaxf(acc[3] + bb4.w, 0.f));
      *(short4_t*)(myh + lr * 140 + n0) = hp;
    }
    short8 a2[4];
    #pragma unroll
    for (int s = 0; s < 4; ++s)
      a2[s] = *(const short8*)(myh + lr * 140 + s * 32 + lg * 8);
    #pragma unroll
    for (int nt = 0; nt < 8; ++nt) {
      #pragma unroll
      for (int s = 0; s < 4; ++s) {
        short8 b = *(const short8*)(W2T + (size_t)(nt * 16 + lr) * HIDD + c * 128 + s * 32 + lg * 8);
        yacc[nt] = __builtin_amdgcn_mfma_f32_16x16x32_bf16(b, a2[s], yacc[nt], 0, 0, 0);
      }
    }
  }

  const int rr = row0 + w * 16 + lr;
  const float mk = mask[rr];
  #pragma unroll
  for (int nt = 0; nt < 8; ++nt) {
    const int n0 = nt * 16 + lg * 4;
    const float4 bb4 = *(const float4*)(bm2 + n0);
    const ushort4 xv = *(const ushort4*)(xls + (w * 16 + lr) * 136 + n0);
    f32x4 out;
    out[0] = (yacc[nt][0] + bb4.x + bf2f(xv.x)) * mk;
    out[1] = (yacc[nt][1] + bb4.y + bf2f(xv.y)) * mk;
    out[2] = (yacc[nt][2] + bb4.z + bf2f(xv.z)) * mk;
    out[3] = (yacc[nt][3] + bb4.w + bf2f(xv.w)) * mk;
    *(f32x4*)(y + (size_t)rr * DDIM + n0) = out;
  }
}

// ---------------- launch ----------------
extern "C" void kernel_launch(void* const* d_in, const int* in_sizes, int n_in,
                              void* d_out, int out_size, void* d_ws, size_t ws_size,
                              hipStream_t stream) {
  const float* seq  = (const float*)d_in[0];
  const float* mask = (const float*)d_in[1];
  const float* Wq = (const float*)d_in[2];
  const float* bq = (const float*)d_in[3];
  const float* Wk = (const float*)d_in[4];
  const float* bk = (const float*)d_in[5];
  const float* Wv = (const float*)d_in[6];
  const float* bv = (const float*)d_in[7];
  const float* g1 = (const float*)d_in[8];
  const float* be1 = (const float*)d_in[9];
  const float* g2 = (const float*)d_in[10];
  const float* be2 = (const float*)d_in[11];
  const float* W1 = (const float*)d_in[12];
  const float* bm1 = (const float*)d_in[13];
  const float* W2 = (const float*)d_in[14];
  const float* bm2 = (const float*)d_in[15];

  // workspace layout (~118 MB)
  float* ws   = (float*)d_ws;
  float* xb   = ws;                                   // 8,388,608 f32 (attn out)
  float* qmk  = ws + 8388608;                         // 65,536 f32
  float* kmk  = ws + 8454144;                         // 65,536 f32
  ushort_t* sbase  = (ushort_t*)(ws + 8519680);
  ushort_t* Qb     = sbase;                           // 8,388,608 bf16
  ushort_t* Kb     = sbase + 8388608;
  ushort_t* Vb     = sbase + 16777216;
  ushort_t* q_in16 = sbase + 25165824;
  ushort_t* seq16  = sbase + 33554432;
  ushort_t* WqT    = sbase + 41943040;                // 16,384
  ushort_t* WkT    = WqT + 16384;
  ushort_t* WvT    = WkT + 16384;
  ushort_t* W1T    = WvT + 16384;                     // 65,536
  ushort_t* W2T    = W1T + 65536;                     // 65,536

  float* y    = (float*)d_out;                        // [B*S*D]
  float* attn = y + 8388608;                          // [B*H*S*S]

  hipLaunchKernelGGL(k_cvtw, dim3(176), dim3(256), 0, stream,
                     Wq, Wk, Wv, W1, W2, WqT, WkT, WvT, W1T, W2T);
  hipLaunchKernelGGL(k_ln1, dim3(BB * SS / 8), dim3(256), 0, stream,
                     seq, g1, be1, q_in16, seq16, qmk, kmk);
  hipLaunchKernelGGL(k_qkv_mfma, dim3(1024, 2), dim3(256), 0, stream,
                     q_in16, seq16, WqT, WkT, WvT, bq, bk, bv, Qb, Kb, Vb);
  hipLaunchKernelGGL(k_attn_mfma, dim3(16 * NH * BB), dim3(256), 0, stream,
                     Qb, Kb, Vb, qmk, kmk, attn, xb);
  hipLaunchKernelGGL(k_mlp_fused, dim3(1024), dim3(256), 0, stream,
                     xb, q_in16, g2, be2, W1T, bm1, W2T, bm2, mask, y);
}

// Round 17
// 550.228 us; speedup vs baseline: 1.0206x; 1.0206x over previous
//
#include <hip/hip_runtime.h>
#include <cstddef>
#include <cstdint>

// Problem constants
#define BB 64
#define SS 1024
#define DDIM 128
#define NH 4
#define HDIM 32
#define HIDD 512
#define EPSF 1e-5f
#define SCALEF 0.17677669529663687f   // 1/sqrt(32)
#define LOG2E 1.4426950408889634f

typedef __attribute__((ext_vector_type(8))) short short8;
typedef __attribute__((ext_vector_type(4))) short short4_t;
typedef __attribute__((ext_vector_type(4))) float f32x4;
typedef unsigned short ushort_t;

__device__ __forceinline__ unsigned short f2bf(float f) {
  unsigned u = __builtin_bit_cast(unsigned, f);
  unsigned r = (u + 0x7FFFu + ((u >> 16) & 1u)) >> 16;
  return (unsigned short)r;
}
__device__ __forceinline__ float bf2f(ushort_t h) {
  unsigned u = ((unsigned)h) << 16;
  return __builtin_bit_cast(float, u);
}

// ---------------- K0: weight transpose+convert via LDS tiles ----------------
__global__ __launch_bounds__(256) void k_cvtw(
    const float* __restrict__ Wq, const float* __restrict__ Wk,
    const float* __restrict__ Wv, const float* __restrict__ W1,
    const float* __restrict__ W2,
    ushort_t* __restrict__ WqT, ushort_t* __restrict__ WkT,
    ushort_t* __restrict__ WvT, ushort_t* __restrict__ W1T,
    ushort_t* __restrict__ W2T) {
  __shared__ float tile[32][33];
  const int bid = blockIdx.x;
  const float* src; ushort_t* dst; int K, N, t0;
  if (bid < 16)       { src = Wq; dst = WqT; K = 128; N = 128; t0 = bid; }
  else if (bid < 32)  { src = Wk; dst = WkT; K = 128; N = 128; t0 = bid - 16; }
  else if (bid < 48)  { src = Wv; dst = WvT; K = 128; N = 128; t0 = bid - 32; }
  else if (bid < 112) { src = W1; dst = W1T; K = 128; N = 512; t0 = bid - 48; }
  else                { src = W2; dst = W2T; K = 512; N = 128; t0 = bid - 112; }
  const int ntile = N >> 5;
  const int k0 = (t0 / ntile) * 32, n0 = (t0 % ntile) * 32;
  const int t = threadIdx.x;
  const int r = t >> 3, c = (t & 7) * 4;
  float4 v = *(const float4*)(src + (size_t)(k0 + r) * N + n0 + c);
  tile[r][c] = v.x; tile[r][c + 1] = v.y; tile[r][c + 2] = v.z; tile[r][c + 3] = v.w;
  __syncthreads();
  ushort4 o;
  o.x = f2bf(tile[c + 0][r]); o.y = f2bf(tile[c + 1][r]);
  o.z = f2bf(tile[c + 2][r]); o.w = f2bf(tile[c + 3][r]);
  *(ushort4*)(dst + (size_t)(n0 + r) * K + k0 + c) = o;
}

// ---------------- K1: LN1 + masks, 32 lanes/row, float4 ----------------
__global__ __launch_bounds__(256) void k_ln1(const float* __restrict__ seq,
    const float* __restrict__ g1, const float* __restrict__ be1,
    ushort_t* __restrict__ q_in16, ushort_t* __restrict__ seq16,
    float* __restrict__ qmask, float* __restrict__ kmask) {
  const int t = threadIdx.x;
  const int r = t >> 5, cl = (t & 31) * 4;
  const int row = blockIdx.x * 8 + r;
  const size_t base = (size_t)row * DDIM + cl;
  const f32x4 v4 = *(const f32x4*)(seq + base);
  float sum = v4[0] + v4[1] + v4[2] + v4[3];
  float asum = fabsf(v4[0]) + fabsf(v4[1]) + fabsf(v4[2]) + fabsf(v4[3]);
  #pragma unroll
  for (int o = 1; o < 32; o <<= 1) { sum += __shfl_xor(sum, o); asum += __shfl_xor(asum, o); }
  const float mean = sum * (1.f / DDIM);
  f32x4 d;
  #pragma unroll
  for (int j = 0; j < 4; ++j) d[j] = v4[j] - mean;
  float sq = d[0] * d[0] + d[1] * d[1] + d[2] * d[2] + d[3] * d[3];
  #pragma unroll
  for (int o = 1; o < 32; o <<= 1) sq += __shfl_xor(sq, o);
  const float rsq = rsqrtf(sq * (1.f / DDIM) + EPSF);
  const float4 g4 = *(const float4*)(g1 + cl);
  const float4 b4 = *(const float4*)(be1 + cl);
  float qv[4];
  qv[0] = d[0] * rsq * g4.x + b4.x; qv[1] = d[1] * rsq * g4.y + b4.y;
  qv[2] = d[2] * rsq * g4.z + b4.z; qv[3] = d[3] * rsq * g4.w + b4.w;
  short4_t q4, s4;
  #pragma unroll
  for (int j = 0; j < 4; ++j) { q4[j] = (short)f2bf(qv[j]); s4[j] = (short)f2bf(v4[j]); }
  *(short4_t*)(q_in16 + base) = q4;
  *(short4_t*)(seq16 + base) = s4;
  float aq = fabsf(qv[0]) + fabsf(qv[1]) + fabsf(qv[2]) + fabsf(qv[3]);
  #pragma unroll
  for (int o = 1; o < 32; o <<= 1) aq += __shfl_xor(aq, o);
  if ((t & 31) == 0) {
    kmask[row] = asum > 0.f ? 1.f : 0.f;
    qmask[row] = aq > 0.f ? 1.f : 0.f;
  }
}

// ---------------- K2: QKV projections via MFMA (Q | K+V merged) ----------------
__global__ __launch_bounds__(256) void k_qkv_mfma(
    const ushort_t* __restrict__ q_in16, const ushort_t* __restrict__ seq16,
    const ushort_t* __restrict__ WqT, const ushort_t* __restrict__ WkT,
    const ushort_t* __restrict__ WvT,
    const float* __restrict__ bq, const float* __restrict__ bk,
    const float* __restrict__ bv,
    ushort_t* __restrict__ Qo, ushort_t* __restrict__ Ko,
    ushort_t* __restrict__ Vo) {
  const int m = blockIdx.y;
  const int t = threadIdx.x, w = t >> 6, lane = t & 63;
  const int lr = lane & 15, lg = lane >> 4;
  const int row = blockIdx.x * 64 + w * 16;

  if (m == 0) {
    const float sc = SCALEF * LOG2E;
    short8 a[4];
    #pragma unroll
    for (int s = 0; s < 4; ++s)
      a[s] = *(const short8*)(q_in16 + (size_t)(row + lr) * DDIM + s * 32 + lg * 8);
    #pragma unroll
    for (int nt = 0; nt < 8; ++nt) {
      f32x4 acc = {0.f, 0.f, 0.f, 0.f};
      #pragma unroll
      for (int s = 0; s < 4; ++s) {
        short8 b = *(const short8*)(WqT + (size_t)(nt * 16 + lr) * DDIM + s * 32 + lg * 8);
        acc = __builtin_amdgcn_mfma_f32_16x16x32_bf16(b, a[s], acc, 0, 0, 0);
      }
      const int n0 = nt * 16 + lg * 4;
      const float4 bb4 = *(const float4*)(bq + n0);
      short4_t o4;
      o4[0] = (short)f2bf((acc[0] + bb4.x) * sc);
      o4[1] = (short)f2bf((acc[1] + bb4.y) * sc);
      o4[2] = (short)f2bf((acc[2] + bb4.z) * sc);
      o4[3] = (short)f2bf((acc[3] + bb4.w) * sc);
      *(short4_t*)(Qo + (size_t)(row + lr) * DDIM + n0) = o4;
    }
  } else {
    short8 a[4];
    #pragma unroll
    for (int s = 0; s < 4; ++s)
      a[s] = *(const short8*)(seq16 + (size_t)(row + lr) * DDIM + s * 32 + lg * 8);
    #pragma unroll
    for (int nt = 0; nt < 8; ++nt) {
      f32x4 accK = {0.f, 0.f, 0.f, 0.f}, accV = {0.f, 0.f, 0.f, 0.f};
      #pragma unroll
      for (int s = 0; s < 4; ++s) {
        short8 bk8 = *(const short8*)(WkT + (size_t)(nt * 16 + lr) * DDIM + s * 32 + lg * 8);
        short8 bv8 = *(const short8*)(WvT + (size_t)(nt * 16 + lr) * DDIM + s * 32 + lg * 8);
        accK = __builtin_amdgcn_mfma_f32_16x16x32_bf16(bk8, a[s], accK, 0, 0, 0);
        accV = __builtin_amdgcn_mfma_f32_16x16x32_bf16(bv8, a[s], accV, 0, 0, 0);
      }
      const int n0 = nt * 16 + lg * 4;
      const float4 bk4 = *(const float4*)(bk + n0);
      const float4 bv4 = *(const float4*)(bv + n0);
      short4_t k4, v4;
      k4[0] = (short)f2bf(accK[0] + bk4.x); v4[0] = (short)f2bf(accV[0] + bv4.x);
      k4[1] = (short)f2bf(accK[1] + bk4.y); v4[1] = (short)f2bf(accV[1] + bv4.y);
      k4[2] = (short)f2bf(accK[2] + bk4.z); v4[2] = (short)f2bf(accV[2] + bv4.z);
      k4[3] = (short)f2bf(accK[3] + bk4.w); v4[3] = (short)f2bf(accV[3] + bv4.w);
      *(short4_t*)(Ko + (size_t)(row + lr) * DDIM + n0) = k4;
      *(short4_t*)(Vo + (size_t)(row + lr) * DDIM + n0) = v4;
    }
  }
}

// ---------------- K3: attention (R9 structure) + XCD-aware block swizzle --------
// 1D grid 4096. Logical block = (group g = h + 4*b, member m = q-block).
// Physical p = xcd + 8*(m + 16*(g>>3)) with xcd = g&7 -> all 16 blocks of a
// group land on one XCD (K/V panel stays L2-resident; attn writes are nt).
__global__ __launch_bounds__(256) void k_attn_mfma(
    const ushort_t* __restrict__ Q, const ushort_t* __restrict__ K,
    const ushort_t* __restrict__ V,
    const float* __restrict__ qmask, const float* __restrict__ kmask,
    float* __restrict__ attn, float* __restrict__ xo) {
  __shared__ __align__(16) ushort_t Ks[2][64 * 40];   // K chunk [k][d]
  __shared__ __align__(16) ushort_t Vts[2][32 * 72];  // V^T chunk [d][k]
  __shared__ __align__(16) ushort_t Wb[4][16 * 88];

  const int t = threadIdx.x;
  const int w = t >> 6, lane = t & 63, lr = lane & 15, lg = lane >> 4;
  // decode swizzled block id
  const int p = blockIdx.x;
  const int xcd = p & 7, kk_ = p >> 3;
  const int m = kk_ & 15, ghi = kk_ >> 4;
  const int g = xcd + 8 * ghi;          // g = h + 4*b
  const int h = g & 3, b = g >> 2;
  const int qi = 15 - m;                // heavy blocks dispatch first
  const int q0 = qi << 6;
  const int kend = q0 + 64;
  const int nch = kend >> 6;

  const size_t bS = (size_t)b * SS;
  const ushort_t* Qh = Q + bS * DDIM + h * HDIM;
  const ushort_t* Kh = K + bS * DDIM + h * HDIM;
  const ushort_t* Vh = V + bS * DDIM + h * HDIM;
  float* attn_bh = attn + (size_t)(b * NH + h) * ((size_t)SS * SS);

  // zero-fill attn[q0:q0+64, kend:SS) with nontemporal stores
  {
    const int cnt4 = (SS - kend) >> 2;
    const f32x4 z = {0.f, 0.f, 0.f, 0.f};
    for (int r = w; r < 64; r += 4) {
      float* rowp = attn_bh + (size_t)(q0 + r) * SS + kend;
      for (int c = lane; c < cnt4; c += 64)
        __builtin_nontemporal_store(z, (f32x4*)(rowp + (size_t)c * 4));
    }
  }

  const int qrow = q0 + w * 16 + lr;       // this lane's q-row
  const short8 qf = *(const short8*)(Qh + (size_t)qrow * DDIM + lg * 8);

  // cooperative staging indices: thread t loads K row (t>>2), 16B slice (t&3)
  const int skr = t >> 2, skc = (t & 3) * 8;

  // ---- pass 1: per-lane partial sums of exp2(s'), double-buffered K ----
  float lsum = 0.f;
  {
    short8 kreg = *(const short8*)(Kh + (size_t)skr * DDIM + skc);
    *(short8*)(Ks[0] + skr * 40 + skc) = kreg;
    __syncthreads();
    for (int c = 0; c < nch; ++c) {
      const int kc = c << 6;
      const int cur = c & 1;
      if (c + 1 < nch)
        kreg = *(const short8*)(Kh + (size_t)(kc + 64 + skr) * DDIM + skc);
      short8 kf[4];
      #pragma unroll
      for (int T = 0; T < 4; ++T)
        kf[T] = *(const short8*)(Ks[cur] + (T * 16 + lr) * 40 + lg * 8);
      f32x4 acc[4];
      #pragma unroll
      for (int T = 0; T < 4; ++T)
        acc[T] = __builtin_amdgcn_mfma_f32_16x16x32_bf16(kf[T], qf,
                                                         (f32x4){0.f, 0.f, 0.f, 0.f}, 0, 0, 0);
      #pragma unroll
      for (int T = 0; T < 4; ++T) {
        const int k0 = kc + T * 16 + lg * 4;
        const float4 km4 = *(const float4*)(kmask + bS + k0);
        #pragma unroll
        for (int r = 0; r < 4; ++r) {
          const float kmv = r == 0 ? km4.x : (r == 1 ? km4.y : (r == 2 ? km4.z : km4.w));
          const bool dead = (kmv == 0.f) || (k0 + r > qrow);
          lsum += dead ? 0.f : exp2f(acc[T][r]);
        }
      }
      if (c + 1 < nch)
        *(short8*)(Ks[cur ^ 1] + skr * 40 + skc) = kreg;
      __syncthreads();
    }
  }
  float ssum = lsum;
  ssum += __shfl_xor(ssum, 16);
  ssum += __shfl_xor(ssum, 32);
  const float qm = qmask[bS + qrow];
  const float inv = (ssum > 0.f) ? qm / ssum : 0.f;

  // ---- pass 2: recompute scores, nt f32x4 attn stores, PV via MFMA (O^T) ----
  ushort_t* myW = &Wb[w][0];
  f32x4 o0 = {0.f, 0.f, 0.f, 0.f}, o1 = {0.f, 0.f, 0.f, 0.f};

  {
    short8 kreg = *(const short8*)(Kh + (size_t)skr * DDIM + skc);
    short8 vreg = *(const short8*)(Vh + (size_t)lane * DDIM + w * 8);
    *(short8*)(Ks[0] + skr * 40 + skc) = kreg;
    #pragma unroll
    for (int j = 0; j < 8; ++j) Vts[0][(w * 8 + j) * 72 + lane] = (ushort_t)vreg[j];
    __syncthreads();
    for (int c = 0; c < nch; ++c) {
      const int kc = c << 6;
      const int cur = c & 1;
      if (c + 1 < nch) {
        kreg = *(const short8*)(Kh + (size_t)(kc + 64 + skr) * DDIM + skc);
        vreg = *(const short8*)(Vh + (size_t)(kc + 64 + lane) * DDIM + w * 8);
      }
      short8 kf[4];
      #pragma unroll
      for (int T = 0; T < 4; ++T)
        kf[T] = *(const short8*)(Ks[cur] + (T * 16 + lr) * 40 + lg * 8);
      f32x4 acc[4];
      #pragma unroll
      for (int T = 0; T < 4; ++T)
        acc[T] = __builtin_amdgcn_mfma_f32_16x16x32_bf16(kf[T], qf,
                                                         (f32x4){0.f, 0.f, 0.f, 0.f}, 0, 0, 0);
      #pragma unroll
      for (int T = 0; T < 4; ++T) {
        const int k0 = kc + T * 16 + lg * 4;
        const float4 km4 = *(const float4*)(kmask + bS + k0);
        f32x4 wv4;
        #pragma unroll
        for (int r = 0; r < 4; ++r) {
          const float kmv = r == 0 ? km4.x : (r == 1 ? km4.y : (r == 2 ? km4.z : km4.w));
          const bool dead = (kmv == 0.f) || (k0 + r > qrow);
          wv4[r] = dead ? 0.f : exp2f(acc[T][r]) * inv;
        }
        __builtin_nontemporal_store(wv4, (f32x4*)(attn_bh + (size_t)qrow * SS + k0));
        short4_t p4;
        p4[0] = (short)f2bf(wv4[0]); p4[1] = (short)f2bf(wv4[1]);
        p4[2] = (short)f2bf(wv4[2]); p4[3] = (short)f2bf(wv4[3]);
        *(short4_t*)(myW + lr * 88 + T * 16 + lg * 4) = p4;
      }
      // PV: O^T = mfma(V^T rows, w rows) -> C[d][q]
      const short8 af0 = *(const short8*)(myW + lr * 88 + lg * 8);
      const short8 af1 = *(const short8*)(myW + lr * 88 + 32 + lg * 8);
      const short8 vb00 = *(const short8*)(Vts[cur] + (size_t)(lr) * 72 + lg * 8);
      const short8 vb10 = *(const short8*)(Vts[cur] + (size_t)(lr) * 72 + 32 + lg * 8);
      const short8 vb01 = *(const short8*)(Vts[cur] + (size_t)(16 + lr) * 72 + lg * 8);
      const short8 vb11 = *(const short8*)(Vts[cur] + (size_t)(16 + lr) * 72 + 32 + lg * 8);
      o0 = __builtin_amdgcn_mfma_f32_16x16x32_bf16(vb00, af0, o0, 0, 0, 0);
      o0 = __builtin_amdgcn_mfma_f32_16x16x32_bf16(vb10, af1, o0, 0, 0, 0);
      o1 = __builtin_amdgcn_mfma_f32_16x16x32_bf16(vb01, af0, o1, 0, 0, 0);
      o1 = __builtin_amdgcn_mfma_f32_16x16x32_bf16(vb11, af1, o1, 0, 0, 0);
      if (c + 1 < nch) {
        *(short8*)(Ks[cur ^ 1] + skr * 40 + skc) = kreg;
        #pragma unroll
        for (int j = 0; j < 8; ++j) Vts[cur ^ 1][(w * 8 + j) * 72 + lane] = (ushort_t)vreg[j];
      }
      __syncthreads();
    }
  }

  {
    float* op = xo + (bS + qrow) * DDIM + h * HDIM;
    *(f32x4*)(op + lg * 4) = o0;
    *(f32x4*)(op + 16 + lg * 4) = o1;
  }
}

// ---------------- K4: fused LN2 + MLP + residual + mask ----------------
__global__ __launch_bounds__(256) void k_mlp_fused(
    const float* __restrict__ xo, const ushort_t* __restrict__ q_in16,
    const float* __restrict__ g2, const float* __restrict__ be2,
    const ushort_t* __restrict__ W1T, const float* __restrict__ bm1,
    const ushort_t* __restrict__ W2T, const float* __restrict__ bm2,
    const float* __restrict__ mask, float* __restrict__ y) {
  __shared__ __align__(16) ushort_t xls[64 * 136];   // LN2 output, bf16
  __shared__ __align__(16) ushort_t hs[4][16 * 140];
  const int t = threadIdx.x, w = t >> 6, lane = t & 63;
  const int lr = lane & 15, lg = lane >> 4;
  const int row0 = blockIdx.x * 64;

  {
    const int r = t >> 2, s = t & 3;
    const size_t base = (size_t)(row0 + r) * DDIM + s * 32;
    float v[32];
    float sum = 0.f, sq = 0.f;
    #pragma unroll
    for (int i = 0; i < 4; ++i) {
      const f32x4 x4a = *(const f32x4*)(xo + base + i * 8);
      const f32x4 x4b = *(const f32x4*)(xo + base + i * 8 + 4);
      const short8 q8 = *(const short8*)(q_in16 + base + i * 8);
      #pragma unroll
      for (int j = 0; j < 4; ++j) {
        v[i * 8 + j] = x4a[j] + bf2f((ushort_t)q8[j]);
        v[i * 8 + 4 + j] = x4b[j] + bf2f((ushort_t)q8[4 + j]);
      }
    }
    #pragma unroll
    for (int i = 0; i < 32; ++i) { sum += v[i]; sq += v[i] * v[i]; }
    sum += __shfl_xor(sum, 1); sum += __shfl_xor(sum, 2);
    sq  += __shfl_xor(sq, 1);  sq  += __shfl_xor(sq, 2);
    const float mean = sum * (1.f / DDIM);
    const float var = sq * (1.f / DDIM) - mean * mean;
    const float rsq = rsqrtf(var + EPSF);
    #pragma unroll
    for (int i = 0; i < 8; ++i) {
      const f32x4 g4 = *(const f32x4*)(g2 + s * 32 + i * 4);
      const f32x4 b4 = *(const f32x4*)(be2 + s * 32 + i * 4);
      short4_t o4;
      #pragma unroll
      for (int j = 0; j < 4; ++j)
        o4[j] = (short)f2bf((v[i * 4 + j] - mean) * rsq * g4[j] + b4[j]);
      *(short4_t*)(xls + r * 136 + s * 32 + i * 4) = o4;
    }
  }
  __syncthreads();

  ushort_t* myh = &hs[w][0];
  short8 xa[4];
  #pragma unroll
  for (int s = 0; s < 4; ++s)
    xa[s] = *(const short8*)(xls + (w * 16 + lr) * 136 + s * 32 + lg * 8);

  f32x4 yacc[8];
  #pragma unroll
  for (int i = 0; i < 8; ++i) yacc[i] = (f32x4){0.f, 0.f, 0.f, 0.f};

  for (int c = 0; c < 4; ++c) {
    #pragma unroll
    for (int nt = 0; nt < 8; ++nt) {
      f32x4 acc = {0.f, 0.f, 0.f, 0.f};
      #pragma unroll
      for (int s = 0; s < 4; ++s) {
        short8 b = *(const short8*)(W1T + (size_t)(c * 128 + nt * 16 + lr) * DDIM + s * 32 + lg * 8);
        acc = __builtin_amdgcn_mfma_f32_16x16x32_bf16(b, xa[s], acc, 0, 0, 0);
      }
      const int n0 = nt * 16 + lg * 4;
      const float4 bb4 = *(const float4*)(bm1 + c * 128 + n0);
      short4_t hp;
      hp[0] = (short)f2bf(fmaxf(acc[0] + bb4.x, 0.f));
      hp[1] = (short)f2bf(fmaxf(acc[1] + bb4.y, 0.f));
      hp[2] = (short)f2bf(fmaxf(acc[2] + bb4.z, 0.f));
      hp[3] = (short)f2bf(fmaxf(acc[3] + bb4.w, 0.f));
      *(short4_t*)(myh + lr * 140 + n0) = hp;
    }
    short8 a2[4];
    #pragma unroll
    for (int s = 0; s < 4; ++s)
      a2[s] = *(const short8*)(myh + lr * 140 + s * 32 + lg * 8);
    #pragma unroll
    for (int nt = 0; nt < 8; ++nt) {
      #pragma unroll
      for (int s = 0; s < 4; ++s) {
        short8 b = *(const short8*)(W2T + (size_t)(nt * 16 + lr) * HIDD + c * 128 + s * 32 + lg * 8);
        yacc[nt] = __builtin_amdgcn_mfma_f32_16x16x32_bf16(b, a2[s], yacc[nt], 0, 0, 0);
      }
    }
  }

  const int rr = row0 + w * 16 + lr;
  const float mk = mask[rr];
  #pragma unroll
  for (int nt = 0; nt < 8; ++nt) {
    const int n0 = nt * 16 + lg * 4;
    const float4 bb4 = *(const float4*)(bm2 + n0);
    const ushort4 xv = *(const ushort4*)(xls + (w * 16 + lr) * 136 + n0);
    f32x4 out;
    out[0] = (yacc[nt][0] + bb4.x + bf2f(xv.x)) * mk;
    out[1] = (yacc[nt][1] + bb4.y + bf2f(xv.y)) * mk;
    out[2] = (yacc[nt][2] + bb4.z + bf2f(xv.z)) * mk;
    out[3] = (yacc[nt][3] + bb4.w + bf2f(xv.w)) * mk;
    *(f32x4*)(y + (size_t)rr * DDIM + n0) = out;
  }
}

// ---------------- launch ----------------
extern "C" void kernel_launch(void* const* d_in, const int* in_sizes, int n_in,
                              void* d_out, int out_size, void* d_ws, size_t ws_size,
                              hipStream_t stream) {
  const float* seq  = (const float*)d_in[0];
  const float* mask = (const float*)d_in[1];
  const float* Wq = (const float*)d_in[2];
  const float* bq = (const float*)d_in[3];
  const float* Wk = (const float*)d_in[4];
  const float* bk = (const float*)d_in[5];
  const float* Wv = (const float*)d_in[6];
  const float* bv = (const float*)d_in[7];
  const float* g1 = (const float*)d_in[8];
  const float* be1 = (const float*)d_in[9];
  const float* g2 = (const float*)d_in[10];
  const float* be2 = (const float*)d_in[11];
  const float* W1 = (const float*)d_in[12];
  const float* bm1 = (const float*)d_in[13];
  const float* W2 = (const float*)d_in[14];
  const float* bm2 = (const float*)d_in[15];

  // workspace layout (~118 MB)
  float* ws   = (float*)d_ws;
  float* xb   = ws;                                   // 8,388,608 f32 (attn out)
  float* qmk  = ws + 8388608;                         // 65,536 f32
  float* kmk  = ws + 8454144;                         // 65,536 f32
  ushort_t* sbase  = (ushort_t*)(ws + 8519680);
  ushort_t* Qb     = sbase;                           // 8,388,608 bf16
  ushort_t* Kb     = sbase + 8388608;
  ushort_t* Vb     = sbase + 16777216;
  ushort_t* q_in16 = sbase + 25165824;
  ushort_t* seq16  = sbase + 33554432;
  ushort_t* WqT    = sbase + 41943040;                // 16,384
  ushort_t* WkT    = WqT + 16384;
  ushort_t* WvT    = WkT + 16384;
  ushort_t* W1T    = WvT + 16384;                     // 65,536
  ushort_t* W2T    = W1T + 65536;                     // 65,536

  float* y    = (float*)d_out;                        // [B*S*D]
  float* attn = y + 8388608;                          // [B*H*S*S]

  hipLaunchKernelGGL(k_cvtw, dim3(176), dim3(256), 0, stream,
                     Wq, Wk, Wv, W1, W2, WqT, WkT, WvT, W1T, W2T);
  hipLaunchKernelGGL(k_ln1, dim3(BB * SS / 8), dim3(256), 0, stream,
                     seq, g1, be1, q_in16, seq16, qmk, kmk);
  hipLaunchKernelGGL(k_qkv_mfma, dim3(1024, 2), dim3(256), 0, stream,
                     q_in16, seq16, WqT, WkT, WvT, bq, bk, bv, Qb, Kb, Vb);
  hipLaunchKernelGGL(k_attn_mfma, dim3(16 * NH * BB), dim3(256), 0, stream,
                     Qb, Kb, Vb, qmk, kmk, attn, xb);
  hipLaunchKernelGGL(k_mlp_fused, dim3(1024), dim3(256), 0, stream,
                     xb, q_in16, g2, be2, W1T, bm1, W2T, bm2, mask, y);
}